// Round 1
// baseline (1573.512 us; speedup 1.0000x reference)
//
#include <hip/hip_runtime.h>
#include <hip/hip_bf16.h>
#include <math.h>

#define N_NODES 16384
#define E_EDGES 131072
#define ETOT (E_EDGES + N_NODES)   // 147456 (self-loops appended)
#define BGRAPH 256
#define F_INPUT 78
#define HID 128
#define HEADS 10
#define F1 (HEADS * HID)           // 1280
#define F_CELL 954
#define NEG_SLOPE 0.2f

// ---------- float <-> orderable uint key (for atomicMax on floats) ----------
static __device__ __forceinline__ unsigned fkey(float f) {
    unsigned b = __float_as_uint(f);
    return (b & 0x80000000u) ? ~b : (b | 0x80000000u);
}
static __device__ __forceinline__ float funkey(unsigned k) {
    unsigned b = (k & 0x80000000u) ? (k ^ 0x80000000u) : ~k;
    return __uint_as_float(b);
}

// ---------- generic tiled f32 GEMM: C = act(A@B + bias) ----------
// A [M,K] row-major, B [K,N] row-major. M must be multiple of 64.
// ACT: 0 = none, 1 = relu.  OUT_BF16: store bf16 instead of f32.
template<int ACT, int OUT_BF16>
__global__ void gemm_tiled(const float* __restrict__ A, const float* __restrict__ B,
                           const float* __restrict__ bias, void* __restrict__ Cout,
                           int M, int N, int K)
{
    __shared__ float As[16][64];
    __shared__ float Bs[16][64];
    const int col0 = blockIdx.x * 64;
    const int row0 = blockIdx.y * 64;
    const int t  = threadIdx.x;        // 0..255
    const int tx = t & 15, ty = t >> 4;
    float acc[4][4] = {};
    for (int k0 = 0; k0 < K; k0 += 16) {
#pragma unroll
        for (int i = 0; i < 4; i++) {
            int idx = t + i * 256;
            int m = idx >> 4, kk = idx & 15;
            int gk = k0 + kk;
            As[kk][m] = (gk < K) ? A[(size_t)(row0 + m) * K + gk] : 0.f;
        }
#pragma unroll
        for (int i = 0; i < 4; i++) {
            int idx = t + i * 256;
            int kk = idx >> 6, n = idx & 63;
            int gk = k0 + kk, gn = col0 + n;
            Bs[kk][n] = (gk < K && gn < N) ? B[(size_t)gk * N + gn] : 0.f;
        }
        __syncthreads();
#pragma unroll
        for (int kk = 0; kk < 16; kk++) {
            float4 av = *(const float4*)&As[kk][ty * 4];
            float4 bv = *(const float4*)&Bs[kk][tx * 4];
            float a[4] = {av.x, av.y, av.z, av.w};
            float b[4] = {bv.x, bv.y, bv.z, bv.w};
#pragma unroll
            for (int i = 0; i < 4; i++)
#pragma unroll
                for (int j = 0; j < 4; j++) acc[i][j] = fmaf(a[i], b[j], acc[i][j]);
        }
        __syncthreads();
    }
#pragma unroll
    for (int i = 0; i < 4; i++) {
        int gm = row0 + ty * 4 + i;
#pragma unroll
        for (int j = 0; j < 4; j++) {
            int gn = col0 + tx * 4 + j;
            if (gn < N) {
                float v = acc[i][j];
                if (bias) v += bias[gn];
                if (ACT == 1) v = fmaxf(v, 0.f);
                if (OUT_BF16)
                    ((__hip_bfloat16*)Cout)[(size_t)gm * N + gn] = __float2bfloat16(v);
                else
                    ((float*)Cout)[(size_t)gm * N + gn] = v;
            }
        }
    }
}

// ---------- attention coefficients ----------
// layer 1: H bf16 [N, 10*128]; es/ed [N,10]
__global__ void attn_coef1(const __hip_bfloat16* __restrict__ H,
                           const float* __restrict__ as_, const float* __restrict__ ad_,
                           float* __restrict__ es, float* __restrict__ ed)
{
    int n = blockIdx.x, l = threadIdx.x;  // 64 threads
    const __hip_bfloat16* row = H + (size_t)n * F1;
#pragma unroll
    for (int h = 0; h < HEADS; h++) {
        float hv0 = __bfloat162float(row[h * HID + l]);
        float hv1 = __bfloat162float(row[h * HID + l + 64]);
        float vs = hv0 * as_[h * HID + l] + hv1 * as_[h * HID + l + 64];
        float vd = hv0 * ad_[h * HID + l] + hv1 * ad_[h * HID + l + 64];
#pragma unroll
        for (int o = 32; o > 0; o >>= 1) { vs += __shfl_down(vs, o); vd += __shfl_down(vd, o); }
        if (l == 0) { es[n * HEADS + h] = vs; ed[n * HEADS + h] = vd; }
    }
}

// layer 2: H f32 [N,128]; es/ed [N]
__global__ void attn_coef2(const float* __restrict__ H,
                           const float* __restrict__ as_, const float* __restrict__ ad_,
                           float* __restrict__ es, float* __restrict__ ed)
{
    int n = blockIdx.x, l = threadIdx.x;  // 64 threads
    const float* row = H + (size_t)n * HID;
    float hv0 = row[l], hv1 = row[l + 64];
    float vs = hv0 * as_[l] + hv1 * as_[l + 64];
    float vd = hv0 * ad_[l] + hv1 * ad_[l + 64];
#pragma unroll
    for (int o = 32; o > 0; o >>= 1) { vs += __shfl_down(vs, o); vd += __shfl_down(vd, o); }
    if (l == 0) { es[n] = vs; ed[n] = vd; }
}

// ---------- edge passes, layer 1 (10 heads) ----------
__global__ void edge_max1(const int* __restrict__ ei, const float* __restrict__ es,
                          const float* __restrict__ ed, unsigned* __restrict__ mk)
{
    int e = blockIdx.x * blockDim.x + threadIdx.x;
    if (e >= ETOT) return;
    int src, dst;
    if (e < E_EDGES) { src = ei[e]; dst = ei[E_EDGES + e]; } else { src = dst = e - E_EDGES; }
#pragma unroll
    for (int h = 0; h < HEADS; h++) {
        float v = es[src * HEADS + h] + ed[dst * HEADS + h];
        v = (v >= 0.f) ? v : NEG_SLOPE * v;
        atomicMax(&mk[dst * HEADS + h], fkey(v));
    }
}

// one wave per edge: softmax weight + scatter-add of w*H[src] into acc[dst]
__global__ void edge_sum1(const int* __restrict__ ei,
                          const float* __restrict__ es, const float* __restrict__ ed,
                          const unsigned* __restrict__ mk, const __hip_bfloat16* __restrict__ H,
                          float* __restrict__ den, float* __restrict__ acc)
{
    int gid = blockIdx.x * blockDim.x + threadIdx.x;
    int e = gid >> 6, l = gid & 63;
    if (e >= ETOT) return;
    int src, dst;
    if (e < E_EDGES) { src = ei[e]; dst = ei[E_EDGES + e]; } else { src = dst = e - E_EDGES; }
    float w[HEADS];
#pragma unroll
    for (int h = 0; h < HEADS; h++) {
        float v = es[src * HEADS + h] + ed[dst * HEADS + h];
        v = (v >= 0.f) ? v : NEG_SLOPE * v;
        w[h] = expf(v - funkey(mk[dst * HEADS + h]));
    }
    if (l < HEADS) atomicAdd(&den[dst * HEADS + l], w[l]);
    const __hip_bfloat16* hrow = H + (size_t)src * F1;
    float* arow = acc + (size_t)dst * F1;
#pragma unroll
    for (int it = 0; it < F1 / 64; it++) {   // 20 iterations; head = it>>1 (compile-time)
        int j = it * 64 + l;
        atomicAdd(&arow[j], w[it >> 1] * __bfloat162float(hrow[j]));
    }
}

__global__ void finalize1(float* __restrict__ acc, const float* __restrict__ den,
                          const float* __restrict__ b)
{
    size_t idx = (size_t)blockIdx.x * blockDim.x + threadIdx.x;
    if (idx >= (size_t)N_NODES * F1) return;
    int n = (int)(idx / F1), j = (int)(idx % F1);
    float v = acc[idx] / den[n * HEADS + (j >> 7)] + b[j];
    acc[idx] = (v > 0.f) ? v : expm1f(v);   // elu
}

// ---------- edge passes, layer 2 (1 head, 128 ch) ----------
__global__ void edge_max2(const int* __restrict__ ei, const float* __restrict__ es,
                          const float* __restrict__ ed, unsigned* __restrict__ mk)
{
    int e = blockIdx.x * blockDim.x + threadIdx.x;
    if (e >= ETOT) return;
    int src, dst;
    if (e < E_EDGES) { src = ei[e]; dst = ei[E_EDGES + e]; } else { src = dst = e - E_EDGES; }
    float v = es[src] + ed[dst];
    v = (v >= 0.f) ? v : NEG_SLOPE * v;
    atomicMax(&mk[dst], fkey(v));
}

__global__ void edge_sum2(const int* __restrict__ ei,
                          const float* __restrict__ es, const float* __restrict__ ed,
                          const unsigned* __restrict__ mk, const float* __restrict__ H,
                          float* __restrict__ den, float* __restrict__ acc)
{
    int gid = blockIdx.x * blockDim.x + threadIdx.x;
    int e = gid >> 6, l = gid & 63;
    if (e >= ETOT) return;
    int src, dst;
    if (e < E_EDGES) { src = ei[e]; dst = ei[E_EDGES + e]; } else { src = dst = e - E_EDGES; }
    float v = es[src] + ed[dst];
    v = (v >= 0.f) ? v : NEG_SLOPE * v;
    float wv = expf(v - funkey(mk[dst]));
    if (l == 0) atomicAdd(&den[dst], wv);
    const float* hrow = H + (size_t)src * HID;
    float* arow = acc + (size_t)dst * HID;
#pragma unroll
    for (int it = 0; it < 2; it++) {
        int j = it * 64 + l;
        atomicAdd(&arow[j], wv * hrow[j]);
    }
}

__global__ void finalize2(float* __restrict__ acc, const float* __restrict__ den,
                          const float* __restrict__ b)
{
    int idx = blockIdx.x * blockDim.x + threadIdx.x;
    if (idx >= N_NODES * HID) return;
    int n = idx >> 7, j = idx & 127;
    float v = acc[idx] / den[n] + b[j];
    acc[idx] = (v > 0.f) ? v : expm1f(v);   // elu
}

// ---------- graph max-pool ----------
__global__ void pool_max(const float* __restrict__ x2, const int* __restrict__ batch,
                         unsigned* __restrict__ pk)
{
    int idx = blockIdx.x * blockDim.x + threadIdx.x;
    if (idx >= N_NODES * HID) return;
    int n = idx >> 7, c = idx & 127;
    atomicMax(&pk[batch[n] * HID + c], fkey(x2[idx]));
}

__global__ void decode_keys(const unsigned* __restrict__ pk, float* __restrict__ out, int count)
{
    int i = blockIdx.x * blockDim.x + threadIdx.x;
    if (i < count) out[i] = funkey(pk[i]);
}

// ---------- cell branch: row L2 normalize ----------
__global__ void cell_norm(const float* __restrict__ cell, float* __restrict__ celln)
{
    int b = blockIdx.x;     // 256 rows
    int t = threadIdx.x;    // 256 threads
    __shared__ float red[256];
    float s = 0.f;
    for (int c = t; c < F_CELL; c += 256) { float v = cell[(size_t)b * F_CELL + c]; s += v * v; }
    red[t] = s; __syncthreads();
    for (int o = 128; o > 0; o >>= 1) { if (t < o) red[t] += red[t + o]; __syncthreads(); }
    float inv = 1.f / fmaxf(sqrtf(red[0]), 1e-12f);
    for (int c = t; c < F_CELL; c += 256)
        celln[(size_t)b * F_CELL + c] = cell[(size_t)b * F_CELL + c] * inv;
}

// ---------- final concat: out[b,0:128]=xg, out[b,128:130]=o2 ----------
__global__ void concat_out(const float* __restrict__ xg, const float* __restrict__ o2,
                           float* __restrict__ out)
{
    int idx = blockIdx.x * blockDim.x + threadIdx.x;
    if (idx >= BGRAPH * 130) return;
    int b = idx / 130, c = idx % 130;
    out[idx] = (c < 128) ? xg[b * HID + c] : o2[b * 2 + (c - 128)];
}

extern "C" void kernel_launch(void* const* d_in, const int* in_sizes, int n_in,
                              void* d_out, int out_size, void* d_ws, size_t ws_size,
                              hipStream_t stream)
{
    const float* x    = (const float*)d_in[0];
    const int*   ei   = (const int*)d_in[1];
    const int*   batch= (const int*)d_in[2];
    const float* cell = (const float*)d_in[3];
    const float* W1   = (const float*)d_in[4];
    const float* as1  = (const float*)d_in[5];
    const float* ad1  = (const float*)d_in[6];
    const float* b1   = (const float*)d_in[7];
    const float* W2   = (const float*)d_in[8];
    const float* as2  = (const float*)d_in[9];
    const float* ad2  = (const float*)d_in[10];
    const float* b2   = (const float*)d_in[11];
    const float* Wg   = (const float*)d_in[12];
    const float* bg   = (const float*)d_in[13];
    const float* Wf1  = (const float*)d_in[14];
    const float* bf1  = (const float*)d_in[15];
    const float* Wf2  = (const float*)d_in[16];
    const float* bf2  = (const float*)d_in[17];
    const float* Wf3  = (const float*)d_in[18];
    const float* bf3  = (const float*)d_in[19];
    const float* Wo   = (const float*)d_in[20];
    const float* bo   = (const float*)d_in[21];
    float* out = (float*)d_out;

    // workspace layout (~150 MB)
    char* w = (char*)d_ws;
    auto alloc = [&](size_t bytes) { char* p = w; w += (bytes + 255) & ~(size_t)255; return p; };
    __hip_bfloat16* H1 = (__hip_bfloat16*)alloc((size_t)N_NODES * F1 * 2);  // 42 MB
    float*    x1   = (float*)alloc((size_t)N_NODES * F1 * 4);               // 84 MB (acc -> x1)
    float*    es1  = (float*)alloc((size_t)N_NODES * HEADS * 4);
    float*    ed1  = (float*)alloc((size_t)N_NODES * HEADS * 4);
    unsigned* m1k  = (unsigned*)alloc((size_t)N_NODES * HEADS * 4);
    float*    den1 = (float*)alloc((size_t)N_NODES * HEADS * 4);
    float*    H2   = (float*)alloc((size_t)N_NODES * HID * 4);              // 8.4 MB
    float*    x2   = (float*)alloc((size_t)N_NODES * HID * 4);              // 8.4 MB
    float*    es2  = (float*)alloc((size_t)N_NODES * 4);
    float*    ed2  = (float*)alloc((size_t)N_NODES * 4);
    unsigned* m2k  = (unsigned*)alloc((size_t)N_NODES * 4);
    float*    den2 = (float*)alloc((size_t)N_NODES * 4);
    unsigned* pk   = (unsigned*)alloc((size_t)BGRAPH * HID * 4);
    float*    pooled=(float*)alloc((size_t)BGRAPH * HID * 4);
    float*    xg   = (float*)alloc((size_t)BGRAPH * HID * 4);
    float*    celln= (float*)alloc((size_t)BGRAPH * F_CELL * 4);
    float*    xc1  = (float*)alloc((size_t)BGRAPH * 2048 * 4);
    float*    xc2  = (float*)alloc((size_t)BGRAPH * 512 * 4);
    float*    xc3  = (float*)alloc((size_t)BGRAPH * HID * 4);
    float*    o2   = (float*)alloc((size_t)BGRAPH * 2 * 4);

    // zero accumulators (re-done every call: deterministic across graph replays)
    hipMemsetAsync(x1,   0, (size_t)N_NODES * F1 * 4, stream);
    hipMemsetAsync(m1k,  0, (size_t)N_NODES * HEADS * 4, stream);
    hipMemsetAsync(den1, 0, (size_t)N_NODES * HEADS * 4, stream);
    hipMemsetAsync(x2,   0, (size_t)N_NODES * HID * 4, stream);
    hipMemsetAsync(m2k,  0, (size_t)N_NODES * 4, stream);
    hipMemsetAsync(den2, 0, (size_t)N_NODES * 4, stream);
    hipMemsetAsync(pk,   0, (size_t)BGRAPH * HID * 4, stream);

    dim3 b256(256);

    // ---- GAT layer 1 ----
    gemm_tiled<0,1><<<dim3(F1/64, N_NODES/64), b256, 0, stream>>>(x, W1, nullptr, H1, N_NODES, F1, F_INPUT);
    attn_coef1<<<N_NODES, 64, 0, stream>>>(H1, as1, ad1, es1, ed1);
    edge_max1<<<(ETOT + 255) / 256, b256, 0, stream>>>(ei, es1, ed1, m1k);
    edge_sum1<<<(ETOT * 64) / 256, b256, 0, stream>>>(ei, es1, ed1, m1k, H1, den1, x1);
    finalize1<<<(int)(((size_t)N_NODES * F1 + 255) / 256), b256, 0, stream>>>(x1, den1, b1);

    // ---- GAT layer 2 ----
    gemm_tiled<0,0><<<dim3(HID/64, N_NODES/64), b256, 0, stream>>>(x1, W2, nullptr, H2, N_NODES, HID, F1);
    attn_coef2<<<N_NODES, 64, 0, stream>>>(H2, as2, ad2, es2, ed2);
    edge_max2<<<(ETOT + 255) / 256, b256, 0, stream>>>(ei, es2, ed2, m2k);
    edge_sum2<<<(ETOT * 64) / 256, b256, 0, stream>>>(ei, es2, ed2, m2k, H2, den2, x2);
    finalize2<<<(N_NODES * HID + 255) / 256, b256, 0, stream>>>(x2, den2, b2);

    // ---- pool + drug fc ----
    pool_max<<<(N_NODES * HID + 255) / 256, b256, 0, stream>>>(x2, batch, pk);
    decode_keys<<<(BGRAPH * HID + 255) / 256, b256, 0, stream>>>(pk, pooled, BGRAPH * HID);
    gemm_tiled<1,0><<<dim3(2, BGRAPH/64), b256, 0, stream>>>(pooled, Wg, bg, xg, BGRAPH, HID, HID);

    // ---- cell branch ----
    cell_norm<<<BGRAPH, 256, 0, stream>>>(cell, celln);
    gemm_tiled<1,0><<<dim3(2048/64, BGRAPH/64), b256, 0, stream>>>(celln, Wf1, bf1, xc1, BGRAPH, 2048, F_CELL);
    gemm_tiled<1,0><<<dim3(512/64,  BGRAPH/64), b256, 0, stream>>>(xc1, Wf2, bf2, xc2, BGRAPH, 512, 2048);
    gemm_tiled<1,0><<<dim3(2,       BGRAPH/64), b256, 0, stream>>>(xc2, Wf3, bf3, xc3, BGRAPH, HID, 512);
    gemm_tiled<0,0><<<dim3(1,       BGRAPH/64), b256, 0, stream>>>(xc3, Wo, bo, o2, BGRAPH, 2, HID);

    // ---- concat output ----
    concat_out<<<(BGRAPH * 130 + 255) / 256, b256, 0, stream>>>(xg, o2, out);
}

// Round 2
// 945.961 us; speedup vs baseline: 1.6634x; 1.6634x over previous
//
#include <hip/hip_runtime.h>
#include <hip/hip_bf16.h>
#include <math.h>

#define N_NODES 16384
#define E_EDGES 131072
#define ETOT (E_EDGES + N_NODES)   // 147456 (self-loops appended)
#define BGRAPH 256
#define F_INPUT 78
#define HID 128
#define HEADS 10
#define F1 (HEADS * HID)           // 1280
#define F_CELL 954
#define NEG_SLOPE 0.2f

// ---------- float <-> orderable uint key (for atomicMax on floats) ----------
static __device__ __forceinline__ unsigned fkey(float f) {
    unsigned b = __float_as_uint(f);
    return (b & 0x80000000u) ? ~b : (b | 0x80000000u);
}
static __device__ __forceinline__ float funkey(unsigned k) {
    unsigned b = (k & 0x80000000u) ? (k ^ 0x80000000u) : ~k;
    return __uint_as_float(b);
}

// ---------- generic tiled f32 GEMM: C = act(A@B + bias) ----------
template<int ACT, int OUT_BF16>
__global__ void gemm_tiled(const float* __restrict__ A, const float* __restrict__ B,
                           const float* __restrict__ bias, void* __restrict__ Cout,
                           int M, int N, int K)
{
    __shared__ float As[16][64];
    __shared__ float Bs[16][64];
    const int col0 = blockIdx.x * 64;
    const int row0 = blockIdx.y * 64;
    const int t  = threadIdx.x;        // 0..255
    const int tx = t & 15, ty = t >> 4;
    float acc[4][4] = {};
    for (int k0 = 0; k0 < K; k0 += 16) {
#pragma unroll
        for (int i = 0; i < 4; i++) {
            int idx = t + i * 256;
            int m = idx >> 4, kk = idx & 15;
            int gk = k0 + kk;
            As[kk][m] = (gk < K) ? A[(size_t)(row0 + m) * K + gk] : 0.f;
        }
#pragma unroll
        for (int i = 0; i < 4; i++) {
            int idx = t + i * 256;
            int kk = idx >> 6, n = idx & 63;
            int gk = k0 + kk, gn = col0 + n;
            Bs[kk][n] = (gk < K && gn < N) ? B[(size_t)gk * N + gn] : 0.f;
        }
        __syncthreads();
#pragma unroll
        for (int kk = 0; kk < 16; kk++) {
            float4 av = *(const float4*)&As[kk][ty * 4];
            float4 bv = *(const float4*)&Bs[kk][tx * 4];
            float a[4] = {av.x, av.y, av.z, av.w};
            float b[4] = {bv.x, bv.y, bv.z, bv.w};
#pragma unroll
            for (int i = 0; i < 4; i++)
#pragma unroll
                for (int j = 0; j < 4; j++) acc[i][j] = fmaf(a[i], b[j], acc[i][j]);
        }
        __syncthreads();
    }
#pragma unroll
    for (int i = 0; i < 4; i++) {
        int gm = row0 + ty * 4 + i;
#pragma unroll
        for (int j = 0; j < 4; j++) {
            int gn = col0 + tx * 4 + j;
            if (gn < N) {
                float v = acc[i][j];
                if (bias) v += bias[gn];
                if (ACT == 1) v = fmaxf(v, 0.f);
                if (OUT_BF16)
                    ((__hip_bfloat16*)Cout)[(size_t)gm * N + gn] = __float2bfloat16(v);
                else
                    ((float*)Cout)[(size_t)gm * N + gn] = v;
            }
        }
    }
}

// ---------- CSR build (by dst) ----------
__global__ void hist_dst(const int* __restrict__ ei, int* __restrict__ counts)
{
    int e = blockIdx.x * blockDim.x + threadIdx.x;
    if (e >= ETOT) return;
    int dst = (e < E_EDGES) ? ei[E_EDGES + e] : (e - E_EDGES);
    atomicAdd(&counts[dst], 1);
}

// single block, 256 threads, each owns 64 contiguous entries
__global__ void scan_counts(const int* __restrict__ counts,
                            int* __restrict__ row_start, int* __restrict__ cursor)
{
    __shared__ int part[256];
    int t = threadIdx.x;
    int base = t * 64;
    int sum = 0;
    for (int i = 0; i < 64; i++) sum += counts[base + i];
    part[t] = sum;
    __syncthreads();
    for (int o = 1; o < 256; o <<= 1) {
        int v = 0;
        if (t >= o) v = part[t - o];
        __syncthreads();
        part[t] += v;
        __syncthreads();
    }
    int run = (t == 0) ? 0 : part[t - 1];
    for (int i = 0; i < 64; i++) {
        row_start[base + i] = run;
        cursor[base + i] = run;
        run += counts[base + i];
    }
    if (t == 255) row_start[N_NODES] = run;
}

__global__ void scatter_csr(const int* __restrict__ ei, int* __restrict__ cursor,
                            int* __restrict__ csr_src)
{
    int e = blockIdx.x * blockDim.x + threadIdx.x;
    if (e >= ETOT) return;
    int src, dst;
    if (e < E_EDGES) { src = ei[e]; dst = ei[E_EDGES + e]; } else { src = dst = e - E_EDGES; }
    int pos = atomicAdd(&cursor[dst], 1);
    csr_src[pos] = src;
}

// ---------- attention coefficients ----------
__global__ void attn_coef1(const __hip_bfloat16* __restrict__ H,
                           const float* __restrict__ as_, const float* __restrict__ ad_,
                           float* __restrict__ es, float* __restrict__ ed)
{
    int n = blockIdx.x, l = threadIdx.x;  // 64 threads
    const __hip_bfloat16* row = H + (size_t)n * F1;
#pragma unroll
    for (int h = 0; h < HEADS; h++) {
        float hv0 = __bfloat162float(row[h * HID + l]);
        float hv1 = __bfloat162float(row[h * HID + l + 64]);
        float vs = hv0 * as_[h * HID + l] + hv1 * as_[h * HID + l + 64];
        float vd = hv0 * ad_[h * HID + l] + hv1 * ad_[h * HID + l + 64];
#pragma unroll
        for (int o = 32; o > 0; o >>= 1) { vs += __shfl_down(vs, o); vd += __shfl_down(vd, o); }
        if (l == 0) { es[n * HEADS + h] = vs; ed[n * HEADS + h] = vd; }
    }
}

__global__ void attn_coef2(const float* __restrict__ H,
                           const float* __restrict__ as_, const float* __restrict__ ad_,
                           float* __restrict__ es, float* __restrict__ ed)
{
    int n = blockIdx.x, l = threadIdx.x;  // 64 threads
    const float* row = H + (size_t)n * HID;
    float hv0 = row[l], hv1 = row[l + 64];
    float vs = hv0 * as_[l] + hv1 * as_[l + 64];
    float vd = hv0 * ad_[l] + hv1 * ad_[l + 64];
#pragma unroll
    for (int o = 32; o > 0; o >>= 1) { vs += __shfl_down(vs, o); vd += __shfl_down(vd, o); }
    if (l == 0) { es[n] = vs; ed[n] = vd; }
}

// ---------- fused GAT layer-1 aggregation: block per dst node ----------
// max -> softmax w -> den -> weighted sum -> /den + bias -> elu. No global atomics.
__global__ __launch_bounds__(256) void gat1_agg(
    const int* __restrict__ row_start, const int* __restrict__ csr_src,
    const __hip_bfloat16* __restrict__ H,
    const float* __restrict__ es, const float* __restrict__ ed,
    const float* __restrict__ b, float* __restrict__ xout)
{
    int n = blockIdx.x, t = threadIdx.x;
    int rs = row_start[n];
    int deg = row_start[n + 1] - rs;

    __shared__ float em[HEADS][256];     // 10 KB (pass A reduce)
    __shared__ float w_s[256][HEADS];    // 10 KB (chunk weights)
    __shared__ int   src_s[256];
    __shared__ float m_s[HEADS];
    __shared__ float den_s[HEADS];

    float edv[HEADS];
#pragma unroll
    for (int h = 0; h < HEADS; h++) edv[h] = ed[n * HEADS + h];

    // ---- pass A: per-head max over incoming edges ----
    float lm[HEADS];
#pragma unroll
    for (int h = 0; h < HEADS; h++) lm[h] = -INFINITY;
    for (int e = t; e < deg; e += 256) {
        int s = csr_src[rs + e];
#pragma unroll
        for (int h = 0; h < HEADS; h++) {
            float v = es[s * HEADS + h] + edv[h];
            v = (v >= 0.f) ? v : NEG_SLOPE * v;
            lm[h] = fmaxf(lm[h], v);
        }
    }
#pragma unroll
    for (int h = 0; h < HEADS; h++) em[h][t] = lm[h];
    __syncthreads();
    for (int o = 128; o > 0; o >>= 1) {
        if (t < o) {
#pragma unroll
            for (int h = 0; h < HEADS; h++) em[h][t] = fmaxf(em[h][t], em[h][t + o]);
        }
        __syncthreads();
    }
    if (t < HEADS) { m_s[t] = em[t][0]; den_s[t] = 0.f; }
    __syncthreads();

    // ---- pass B: weights + weighted accumulation (chunks of 256 edges) ----
    float acc[5] = {0.f, 0.f, 0.f, 0.f, 0.f};   // channels t, t+256, ..., t+1024
    for (int base = 0; base < deg; base += 256) {
        int e = base + t;
        if (e < deg) {
            int s = csr_src[rs + e];
            src_s[t] = s;
#pragma unroll
            for (int h = 0; h < HEADS; h++) {
                float v = es[s * HEADS + h] + edv[h];
                v = (v >= 0.f) ? v : NEG_SLOPE * v;
                float wv = __expf(v - m_s[h]);
                w_s[t][h] = wv;
                atomicAdd(&den_s[h], wv);
            }
        }
        __syncthreads();
        int cnt = min(256, deg - base);
        for (int j = 0; j < cnt; j++) {
            int s = src_s[j];
            const __hip_bfloat16* hrow = H + (size_t)s * F1;
#pragma unroll
            for (int i = 0; i < 5; i++) {
                int c = t + i * 256;
                acc[i] = fmaf(w_s[j][c >> 7], __bfloat162float(hrow[c]), acc[i]);
            }
        }
        __syncthreads();
    }

    // ---- epilogue: /den + bias + elu ----
    float* orow = xout + (size_t)n * F1;
#pragma unroll
    for (int i = 0; i < 5; i++) {
        int c = t + i * 256;
        float v = acc[i] / den_s[c >> 7] + b[c];
        orow[c] = (v > 0.f) ? v : expm1f(v);
    }
}

// ---------- fused GAT layer-2 aggregation: one wave per dst node ----------
__global__ __launch_bounds__(64) void gat2_agg(
    const int* __restrict__ row_start, const int* __restrict__ csr_src,
    const float* __restrict__ H,
    const float* __restrict__ es, const float* __restrict__ ed,
    const float* __restrict__ b, float* __restrict__ xout)
{
    int n = blockIdx.x, l = threadIdx.x;
    int rs = row_start[n];
    int deg = row_start[n + 1] - rs;
    float edv = ed[n];

    // max
    float lm = -INFINITY;
    for (int e = l; e < deg; e += 64) {
        int s = csr_src[rs + e];
        float v = es[s] + edv;
        v = (v >= 0.f) ? v : NEG_SLOPE * v;
        lm = fmaxf(lm, v);
    }
#pragma unroll
    for (int o = 32; o > 0; o >>= 1) lm = fmaxf(lm, __shfl_xor(lm, o));

    __shared__ float w_s[64];
    __shared__ int src_s[64];
    float acc0 = 0.f, acc1 = 0.f, den = 0.f;
    for (int base = 0; base < deg; base += 64) {
        int e = base + l;
        float wv = 0.f;
        if (e < deg) {
            int s = csr_src[rs + e];
            src_s[l] = s;
            float v = es[s] + edv;
            v = (v >= 0.f) ? v : NEG_SLOPE * v;
            wv = __expf(v - lm);
        }
        w_s[l] = wv;
        den += wv;
        __syncthreads();
        int cnt = min(64, deg - base);
        for (int j = 0; j < cnt; j++) {
            float wj = w_s[j];
            const float* hrow = H + (size_t)src_s[j] * HID;
            acc0 = fmaf(wj, hrow[l], acc0);
            acc1 = fmaf(wj, hrow[l + 64], acc1);
        }
        __syncthreads();
    }
#pragma unroll
    for (int o = 32; o > 0; o >>= 1) den += __shfl_xor(den, o);

    float v0 = acc0 / den + b[l];
    float v1 = acc1 / den + b[l + 64];
    float* orow = xout + (size_t)n * HID;
    orow[l]      = (v0 > 0.f) ? v0 : expm1f(v0);
    orow[l + 64] = (v1 > 0.f) ? v1 : expm1f(v1);
}

// ---------- graph max-pool ----------
__global__ void pool_max(const float* __restrict__ x2, const int* __restrict__ batch,
                         unsigned* __restrict__ pk)
{
    int idx = blockIdx.x * blockDim.x + threadIdx.x;
    if (idx >= N_NODES * HID) return;
    int n = idx >> 7, c = idx & 127;
    atomicMax(&pk[batch[n] * HID + c], fkey(x2[idx]));
}

__global__ void decode_keys(const unsigned* __restrict__ pk, float* __restrict__ out, int count)
{
    int i = blockIdx.x * blockDim.x + threadIdx.x;
    if (i < count) out[i] = funkey(pk[i]);
}

// ---------- cell branch: row L2 normalize ----------
__global__ void cell_norm(const float* __restrict__ cell, float* __restrict__ celln)
{
    int b = blockIdx.x;     // 256 rows
    int t = threadIdx.x;    // 256 threads
    __shared__ float red[256];
    float s = 0.f;
    for (int c = t; c < F_CELL; c += 256) { float v = cell[(size_t)b * F_CELL + c]; s += v * v; }
    red[t] = s; __syncthreads();
    for (int o = 128; o > 0; o >>= 1) { if (t < o) red[t] += red[t + o]; __syncthreads(); }
    float inv = 1.f / fmaxf(sqrtf(red[0]), 1e-12f);
    for (int c = t; c < F_CELL; c += 256)
        celln[(size_t)b * F_CELL + c] = cell[(size_t)b * F_CELL + c] * inv;
}

// ---------- final concat ----------
__global__ void concat_out(const float* __restrict__ xg, const float* __restrict__ o2,
                           float* __restrict__ out)
{
    int idx = blockIdx.x * blockDim.x + threadIdx.x;
    if (idx >= BGRAPH * 130) return;
    int b = idx / 130, c = idx % 130;
    out[idx] = (c < 128) ? xg[b * HID + c] : o2[b * 2 + (c - 128)];
}

extern "C" void kernel_launch(void* const* d_in, const int* in_sizes, int n_in,
                              void* d_out, int out_size, void* d_ws, size_t ws_size,
                              hipStream_t stream)
{
    const float* x    = (const float*)d_in[0];
    const int*   ei   = (const int*)d_in[1];
    const int*   batch= (const int*)d_in[2];
    const float* cell = (const float*)d_in[3];
    const float* W1   = (const float*)d_in[4];
    const float* as1  = (const float*)d_in[5];
    const float* ad1  = (const float*)d_in[6];
    const float* b1   = (const float*)d_in[7];
    const float* W2   = (const float*)d_in[8];
    const float* as2  = (const float*)d_in[9];
    const float* ad2  = (const float*)d_in[10];
    const float* b2   = (const float*)d_in[11];
    const float* Wg   = (const float*)d_in[12];
    const float* bg   = (const float*)d_in[13];
    const float* Wf1  = (const float*)d_in[14];
    const float* bf1  = (const float*)d_in[15];
    const float* Wf2  = (const float*)d_in[16];
    const float* bf2  = (const float*)d_in[17];
    const float* Wf3  = (const float*)d_in[18];
    const float* bf3  = (const float*)d_in[19];
    const float* Wo   = (const float*)d_in[20];
    const float* bo   = (const float*)d_in[21];
    float* out = (float*)d_out;

    char* w = (char*)d_ws;
    auto alloc = [&](size_t bytes) { char* p = w; w += (bytes + 255) & ~(size_t)255; return p; };
    __hip_bfloat16* H1 = (__hip_bfloat16*)alloc((size_t)N_NODES * F1 * 2);  // 42 MB
    float*    x1   = (float*)alloc((size_t)N_NODES * F1 * 4);               // 84 MB
    float*    es1  = (float*)alloc((size_t)N_NODES * HEADS * 4);
    float*    ed1  = (float*)alloc((size_t)N_NODES * HEADS * 4);
    float*    H2   = (float*)alloc((size_t)N_NODES * HID * 4);
    float*    x2   = (float*)alloc((size_t)N_NODES * HID * 4);
    float*    es2  = (float*)alloc((size_t)N_NODES * 4);
    float*    ed2  = (float*)alloc((size_t)N_NODES * 4);
    int*      counts    = (int*)alloc((size_t)N_NODES * 4);
    int*      row_start = (int*)alloc((size_t)(N_NODES + 1) * 4);
    int*      cursor    = (int*)alloc((size_t)N_NODES * 4);
    int*      csr_src   = (int*)alloc((size_t)ETOT * 4);
    unsigned* pk   = (unsigned*)alloc((size_t)BGRAPH * HID * 4);
    float*    pooled=(float*)alloc((size_t)BGRAPH * HID * 4);
    float*    xg   = (float*)alloc((size_t)BGRAPH * HID * 4);
    float*    celln= (float*)alloc((size_t)BGRAPH * F_CELL * 4);
    float*    xc1  = (float*)alloc((size_t)BGRAPH * 2048 * 4);
    float*    xc2  = (float*)alloc((size_t)BGRAPH * 512 * 4);
    float*    xc3  = (float*)alloc((size_t)BGRAPH * HID * 4);
    float*    o2   = (float*)alloc((size_t)BGRAPH * 2 * 4);

    hipMemsetAsync(counts, 0, (size_t)N_NODES * 4, stream);
    hipMemsetAsync(pk,     0, (size_t)BGRAPH * HID * 4, stream);

    dim3 b256(256);
    const int egrid = (ETOT + 255) / 256;

    // ---- CSR build (shared by both layers) ----
    hist_dst<<<egrid, b256, 0, stream>>>(ei, counts);
    scan_counts<<<1, b256, 0, stream>>>(counts, row_start, cursor);
    scatter_csr<<<egrid, b256, 0, stream>>>(ei, cursor, csr_src);

    // ---- GAT layer 1 ----
    gemm_tiled<0,1><<<dim3(F1/64, N_NODES/64), b256, 0, stream>>>(x, W1, nullptr, H1, N_NODES, F1, F_INPUT);
    attn_coef1<<<N_NODES, 64, 0, stream>>>(H1, as1, ad1, es1, ed1);
    gat1_agg<<<N_NODES, b256, 0, stream>>>(row_start, csr_src, H1, es1, ed1, b1, x1);

    // ---- GAT layer 2 ----
    gemm_tiled<0,0><<<dim3(HID/64, N_NODES/64), b256, 0, stream>>>(x1, W2, nullptr, H2, N_NODES, HID, F1);
    attn_coef2<<<N_NODES, 64, 0, stream>>>(H2, as2, ad2, es2, ed2);
    gat2_agg<<<N_NODES, 64, 0, stream>>>(row_start, csr_src, H2, es2, ed2, b2, x2);

    // ---- pool + drug fc ----
    pool_max<<<(N_NODES * HID + 255) / 256, b256, 0, stream>>>(x2, batch, pk);
    decode_keys<<<(BGRAPH * HID + 255) / 256, b256, 0, stream>>>(pk, pooled, BGRAPH * HID);
    gemm_tiled<1,0><<<dim3(2, BGRAPH/64), b256, 0, stream>>>(pooled, Wg, bg, xg, BGRAPH, HID, HID);

    // ---- cell branch ----
    cell_norm<<<BGRAPH, 256, 0, stream>>>(cell, celln);
    gemm_tiled<1,0><<<dim3(2048/64, BGRAPH/64), b256, 0, stream>>>(celln, Wf1, bf1, xc1, BGRAPH, 2048, F_CELL);
    gemm_tiled<1,0><<<dim3(512/64,  BGRAPH/64), b256, 0, stream>>>(xc1, Wf2, bf2, xc2, BGRAPH, 512, 2048);
    gemm_tiled<1,0><<<dim3(2,       BGRAPH/64), b256, 0, stream>>>(xc2, Wf3, bf3, xc3, BGRAPH, HID, 512);
    gemm_tiled<0,0><<<dim3(1,       BGRAPH/64), b256, 0, stream>>>(xc3, Wo, bo, o2, BGRAPH, 2, HID);

    // ---- concat output ----
    concat_out<<<(BGRAPH * 130 + 255) / 256, b256, 0, stream>>>(xg, o2, out);
}

// Round 3
// 345.430 us; speedup vs baseline: 4.5552x; 2.7385x over previous
//
#include <hip/hip_runtime.h>
#include <hip/hip_bf16.h>
#include <math.h>

#define N_NODES 16384
#define E_EDGES 131072
#define ETOT (E_EDGES + N_NODES)   // 147456 (self-loops appended)
#define BGRAPH 256
#define F_INPUT 78
#define KPAD1 96                   // F_INPUT padded to mult of 32
#define HID 128
#define HEADS 10
#define F1 (HEADS * HID)           // 1280
#define F_CELL 954
#define KPADC 960                  // F_CELL padded
#define NEG_SLOPE 0.2f

typedef __attribute__((ext_vector_type(8))) short frag_t;   // 8 bf16
typedef __attribute__((ext_vector_type(4))) float f4_t;

static __device__ __forceinline__ unsigned fkey(float f) {
    unsigned b = __float_as_uint(f);
    return (b & 0x80000000u) ? ~b : (b | 0x80000000u);
}
static __device__ __forceinline__ float funkey(unsigned k) {
    unsigned b = (k & 0x80000000u) ? (k ^ 0x80000000u) : ~k;
    return __uint_as_float(b);
}
static __device__ __forceinline__ unsigned short f2bf(float f) {
    __hip_bfloat16 h = __float2bfloat16(f);
    return *(unsigned short*)&h;
}

// ================= MFMA bf16 GEMM =================
// A [M,Kpad] bf16, BT [N,Kpad] bf16 (B transposed). C row-major [M,N].
// OUT: 0 = f32 store, 1 = bf16 store, 2 = f32 atomicAdd (split-K).
// grid: x = N/BN, y = M/BM, z = K-splits (each does `ksteps` K-steps of 32).
template<int WM16, int WN16, int OUT>
__global__ __launch_bounds__(256) void mfma_gemm(
    const unsigned short* __restrict__ A, const unsigned short* __restrict__ BT,
    void* __restrict__ C, int M, int N, int Kpad, int ksteps)
{
    constexpr int BM = 32 * WM16, BN = 32 * WN16;
    __shared__ __align__(16) unsigned short Als[BM * 32];
    __shared__ __align__(16) unsigned short Bls[BN * 32];
    const int t = threadIdx.x;
    const int wave = t >> 6, lane = t & 63;
    const int wr = (wave >> 1) * (16 * WM16);
    const int wc = (wave & 1) * (16 * WN16);
    const int row0 = blockIdx.y * BM;
    const int col0 = blockIdx.x * BN;
    int kk = blockIdx.z * ksteps * 32;
    const int kend = min(kk + ksteps * 32, Kpad);

    f4_t acc[WM16][WN16];
#pragma unroll
    for (int m = 0; m < WM16; m++)
#pragma unroll
        for (int n = 0; n < WN16; n++) { acc[m][n] = (f4_t){0.f, 0.f, 0.f, 0.f}; }

    const int lrow = lane & 15, kg = lane >> 4;
    for (; kk < kend; kk += 32) {
#pragma unroll
        for (int p = 0; p < BM / 64; p++) {
            int i = t + p * 256;
            int r = i >> 2, slot = i & 3;
            uint4 v = *(const uint4*)&A[(size_t)(row0 + r) * Kpad + kk + slot * 8];
            *(uint4*)&Als[r * 32 + ((slot ^ (r & 3) ^ ((r >> 2) & 3)) * 8)] = v;
        }
#pragma unroll
        for (int p = 0; p < BN / 64; p++) {
            int i = t + p * 256;
            int r = i >> 2, slot = i & 3;
            uint4 v = *(const uint4*)&BT[(size_t)(col0 + r) * Kpad + kk + slot * 8];
            *(uint4*)&Bls[r * 32 + ((slot ^ (r & 3) ^ ((r >> 2) & 3)) * 8)] = v;
        }
        __syncthreads();
        frag_t af[WM16], bfr[WN16];
#pragma unroll
        for (int m = 0; m < WM16; m++) {
            int r = wr + m * 16 + lrow;
            af[m] = *(frag_t*)&Als[r * 32 + ((kg ^ (r & 3) ^ ((r >> 2) & 3)) * 8)];
        }
#pragma unroll
        for (int n = 0; n < WN16; n++) {
            int r = wc + n * 16 + lrow;
            bfr[n] = *(frag_t*)&Bls[r * 32 + ((kg ^ (r & 3) ^ ((r >> 2) & 3)) * 8)];
        }
#pragma unroll
        for (int m = 0; m < WM16; m++)
#pragma unroll
            for (int n = 0; n < WN16; n++)
                acc[m][n] = __builtin_amdgcn_mfma_f32_16x16x32_bf16(af[m], bfr[n], acc[m][n], 0, 0, 0);
        __syncthreads();
    }

#pragma unroll
    for (int m = 0; m < WM16; m++) {
#pragma unroll
        for (int n = 0; n < WN16; n++) {
            int col = col0 + wc + n * 16 + lrow;
#pragma unroll
            for (int r = 0; r < 4; r++) {
                int row = row0 + wr + m * 16 + kg * 4 + r;
                float v = acc[m][n][r];
                if (OUT == 0)      ((float*)C)[(size_t)row * N + col] = v;
                else if (OUT == 1) ((unsigned short*)C)[(size_t)row * N + col] = f2bf(v);
                else               atomicAdd(&((float*)C)[(size_t)row * N + col], v);
            }
        }
    }
}

// ================= format conversions =================
__global__ void convert_x(const float* __restrict__ x, unsigned short* __restrict__ xb)
{
    int i = blockIdx.x * blockDim.x + threadIdx.x;
    if (i >= N_NODES * KPAD1) return;
    int r = i / KPAD1, k = i % KPAD1;
    xb[i] = (k < F_INPUT) ? f2bf(x[r * F_INPUT + k]) : 0;
}

// W [K,N] f32 -> WT [N,Kpad] bf16 (zero pad K..Kpad)
__global__ void transpose_w(const float* __restrict__ W, unsigned short* __restrict__ WT,
                            int K, int N, int Kpad)
{
    int i = blockIdx.x * blockDim.x + threadIdx.x;
    if (i >= N * Kpad) return;
    int n = i / Kpad, k = i % Kpad;
    WT[i] = (k < K) ? f2bf(W[(size_t)k * N + n]) : 0;
}

// ================= CSR build (by dst) =================
__global__ void hist_dst(const int* __restrict__ ei, int* __restrict__ counts)
{
    int e = blockIdx.x * blockDim.x + threadIdx.x;
    if (e >= ETOT) return;
    int dst = (e < E_EDGES) ? ei[E_EDGES + e] : (e - E_EDGES);
    atomicAdd(&counts[dst], 1);
}

__global__ void scan_counts(const int* __restrict__ counts,
                            int* __restrict__ row_start, int* __restrict__ cursor)
{
    __shared__ int part[256];
    int t = threadIdx.x;
    int base = t * 64;
    int sum = 0;
    for (int i = 0; i < 64; i++) sum += counts[base + i];
    part[t] = sum;
    __syncthreads();
    for (int o = 1; o < 256; o <<= 1) {
        int v = 0;
        if (t >= o) v = part[t - o];
        __syncthreads();
        part[t] += v;
        __syncthreads();
    }
    int run = (t == 0) ? 0 : part[t - 1];
    for (int i = 0; i < 64; i++) {
        row_start[base + i] = run;
        cursor[base + i] = run;
        run += counts[base + i];
    }
    if (t == 255) row_start[N_NODES] = run;
}

__global__ void scatter_csr(const int* __restrict__ ei, int* __restrict__ cursor,
                            int* __restrict__ csr_src)
{
    int e = blockIdx.x * blockDim.x + threadIdx.x;
    if (e >= ETOT) return;
    int src, dst;
    if (e < E_EDGES) { src = ei[e]; dst = ei[E_EDGES + e]; } else { src = dst = e - E_EDGES; }
    int pos = atomicAdd(&cursor[dst], 1);
    csr_src[pos] = src;
}

// ================= attention coefficients =================
__global__ void attn_coef1(const __hip_bfloat16* __restrict__ H,
                           const float* __restrict__ as_, const float* __restrict__ ad_,
                           float* __restrict__ es, float* __restrict__ ed)
{
    int n = blockIdx.x, l = threadIdx.x;  // 64 threads
    const __hip_bfloat16* row = H + (size_t)n * F1;
#pragma unroll
    for (int h = 0; h < HEADS; h++) {
        float hv0 = __bfloat162float(row[h * HID + l]);
        float hv1 = __bfloat162float(row[h * HID + l + 64]);
        float vs = hv0 * as_[h * HID + l] + hv1 * as_[h * HID + l + 64];
        float vd = hv0 * ad_[h * HID + l] + hv1 * ad_[h * HID + l + 64];
#pragma unroll
        for (int o = 32; o > 0; o >>= 1) { vs += __shfl_down(vs, o); vd += __shfl_down(vd, o); }
        if (l == 0) { es[n * HEADS + h] = vs; ed[n * HEADS + h] = vd; }
    }
}

__global__ void attn_coef2(const float* __restrict__ H,
                           const float* __restrict__ as_, const float* __restrict__ ad_,
                           float* __restrict__ es, float* __restrict__ ed)
{
    int n = blockIdx.x, l = threadIdx.x;  // 64 threads
    const float* row = H + (size_t)n * HID;
    float hv0 = row[l], hv1 = row[l + 64];
    float vs = hv0 * as_[l] + hv1 * as_[l + 64];
    float vd = hv0 * ad_[l] + hv1 * ad_[l + 64];
#pragma unroll
    for (int o = 32; o > 0; o >>= 1) { vs += __shfl_down(vs, o); vd += __shfl_down(vd, o); }
    if (l == 0) { es[n] = vs; ed[n] = vd; }
}

// ================= fused GAT layer-1 aggregation (block per dst) =================
__global__ __launch_bounds__(256) void gat1_agg(
    const int* __restrict__ row_start, const int* __restrict__ csr_src,
    const __hip_bfloat16* __restrict__ H,
    const float* __restrict__ es, const float* __restrict__ ed,
    const float* __restrict__ b, unsigned short* __restrict__ xout)
{
    int n = blockIdx.x, t = threadIdx.x;
    int rs = row_start[n];
    int deg = row_start[n + 1] - rs;

    __shared__ float em[HEADS][256];
    __shared__ float w_s[256][HEADS];
    __shared__ int   src_s[256];
    __shared__ float m_s[HEADS];
    __shared__ float den_s[HEADS];

    float edv[HEADS];
#pragma unroll
    for (int h = 0; h < HEADS; h++) edv[h] = ed[n * HEADS + h];

    float lm[HEADS];
#pragma unroll
    for (int h = 0; h < HEADS; h++) lm[h] = -INFINITY;
    for (int e = t; e < deg; e += 256) {
        int s = csr_src[rs + e];
#pragma unroll
        for (int h = 0; h < HEADS; h++) {
            float v = es[s * HEADS + h] + edv[h];
            v = (v >= 0.f) ? v : NEG_SLOPE * v;
            lm[h] = fmaxf(lm[h], v);
        }
    }
#pragma unroll
    for (int h = 0; h < HEADS; h++) em[h][t] = lm[h];
    __syncthreads();
    for (int o = 128; o > 0; o >>= 1) {
        if (t < o) {
#pragma unroll
            for (int h = 0; h < HEADS; h++) em[h][t] = fmaxf(em[h][t], em[h][t + o]);
        }
        __syncthreads();
    }
    if (t < HEADS) { m_s[t] = em[t][0]; den_s[t] = 0.f; }
    __syncthreads();

    float acc[5] = {0.f, 0.f, 0.f, 0.f, 0.f};
    for (int base = 0; base < deg; base += 256) {
        int e = base + t;
        if (e < deg) {
            int s = csr_src[rs + e];
            src_s[t] = s;
#pragma unroll
            for (int h = 0; h < HEADS; h++) {
                float v = es[s * HEADS + h] + edv[h];
                v = (v >= 0.f) ? v : NEG_SLOPE * v;
                float wv = __expf(v - m_s[h]);
                w_s[t][h] = wv;
                atomicAdd(&den_s[h], wv);
            }
        }
        __syncthreads();
        int cnt = min(256, deg - base);
        for (int j = 0; j < cnt; j++) {
            int s = src_s[j];
            const __hip_bfloat16* hrow = H + (size_t)s * F1;
#pragma unroll
            for (int i = 0; i < 5; i++) {
                int c = t + i * 256;
                acc[i] = fmaf(w_s[j][c >> 7], __bfloat162float(hrow[c]), acc[i]);
            }
        }
        __syncthreads();
    }

    unsigned short* orow = xout + (size_t)n * F1;
#pragma unroll
    for (int i = 0; i < 5; i++) {
        int c = t + i * 256;
        float v = acc[i] / den_s[c >> 7] + b[c];
        orow[c] = f2bf((v > 0.f) ? v : expm1f(v));
    }
}

// ================= fused GAT layer-2 aggregation (wave per dst) =================
__global__ __launch_bounds__(64) void gat2_agg(
    const int* __restrict__ row_start, const int* __restrict__ csr_src,
    const float* __restrict__ H,
    const float* __restrict__ es, const float* __restrict__ ed,
    const float* __restrict__ b, float* __restrict__ xout)
{
    int n = blockIdx.x, l = threadIdx.x;
    int rs = row_start[n];
    int deg = row_start[n + 1] - rs;
    float edv = ed[n];

    float lm = -INFINITY;
    for (int e = l; e < deg; e += 64) {
        int s = csr_src[rs + e];
        float v = es[s] + edv;
        v = (v >= 0.f) ? v : NEG_SLOPE * v;
        lm = fmaxf(lm, v);
    }
#pragma unroll
    for (int o = 32; o > 0; o >>= 1) lm = fmaxf(lm, __shfl_xor(lm, o));

    __shared__ float w_s[64];
    __shared__ int src_s[64];
    float acc0 = 0.f, acc1 = 0.f, den = 0.f;
    for (int base = 0; base < deg; base += 64) {
        int e = base + l;
        float wv = 0.f;
        if (e < deg) {
            int s = csr_src[rs + e];
            src_s[l] = s;
            float v = es[s] + edv;
            v = (v >= 0.f) ? v : NEG_SLOPE * v;
            wv = __expf(v - lm);
        }
        w_s[l] = wv;
        den += wv;
        __syncthreads();
        int cnt = min(64, deg - base);
        for (int j = 0; j < cnt; j++) {
            float wj = w_s[j];
            const float* hrow = H + (size_t)src_s[j] * HID;
            acc0 = fmaf(wj, hrow[l], acc0);
            acc1 = fmaf(wj, hrow[l + 64], acc1);
        }
        __syncthreads();
    }
#pragma unroll
    for (int o = 32; o > 0; o >>= 1) den += __shfl_xor(den, o);

    float v0 = acc0 / den + b[l];
    float v1 = acc1 / den + b[l + 64];
    float* orow = xout + (size_t)n * HID;
    orow[l]      = (v0 > 0.f) ? v0 : expm1f(v0);
    orow[l + 64] = (v1 > 0.f) ? v1 : expm1f(v1);
}

// ================= pool / cell / epilogues =================
__global__ void pool_max(const float* __restrict__ x2, const int* __restrict__ batch,
                         unsigned* __restrict__ pk)
{
    int idx = blockIdx.x * blockDim.x + threadIdx.x;
    if (idx >= N_NODES * HID) return;
    int n = idx >> 7, c = idx & 127;
    atomicMax(&pk[batch[n] * HID + c], fkey(x2[idx]));
}

__global__ void decode_keys_bf16(const unsigned* __restrict__ pk, unsigned short* __restrict__ outb,
                                 int count)
{
    int i = blockIdx.x * blockDim.x + threadIdx.x;
    if (i < count) outb[i] = f2bf(funkey(pk[i]));
}

__global__ void cell_norm(const float* __restrict__ cell, unsigned short* __restrict__ celln)
{
    int b = blockIdx.x;     // 256 rows
    int t = threadIdx.x;    // 256 threads
    __shared__ float red[256];
    float s = 0.f;
    for (int c = t; c < F_CELL; c += 256) { float v = cell[(size_t)b * F_CELL + c]; s += v * v; }
    red[t] = s; __syncthreads();
    for (int o = 128; o > 0; o >>= 1) { if (t < o) red[t] += red[t + o]; __syncthreads(); }
    float inv = 1.f / fmaxf(sqrtf(red[0]), 1e-12f);
    for (int c = t; c < KPADC; c += 256) {
        float v = (c < F_CELL) ? cell[(size_t)b * F_CELL + c] * inv : 0.f;
        celln[(size_t)b * KPADC + c] = f2bf(v);
    }
}

// bias + relu; OUT_BF16 selects output type
template<int OUT_BF16>
__global__ void epi_relu(const float* __restrict__ acc, const float* __restrict__ bias,
                         void* __restrict__ out, int rows, int cols)
{
    int i = blockIdx.x * blockDim.x + threadIdx.x;
    if (i >= rows * cols) return;
    int c = i % cols;
    float v = fmaxf(acc[i] + bias[c], 0.f);
    if (OUT_BF16) ((unsigned short*)out)[i] = f2bf(v);
    else          ((float*)out)[i] = v;
}

// o2 = xc3 @ Wo + bo; out = concat(xg, o2)
__global__ void final_out(const float* __restrict__ xg, const float* __restrict__ xc3,
                          const float* __restrict__ Wo, const float* __restrict__ bo,
                          float* __restrict__ out)
{
    int b = blockIdx.x, t = threadIdx.x;   // 128 threads
    float v = xc3[b * HID + t];
    float p0 = v * Wo[t * 2], p1 = v * Wo[t * 2 + 1];
    __shared__ float s[4];
#pragma unroll
    for (int o = 32; o > 0; o >>= 1) { p0 += __shfl_down(p0, o); p1 += __shfl_down(p1, o); }
    if ((t & 63) == 0) { s[(t >> 6) * 2] = p0; s[(t >> 6) * 2 + 1] = p1; }
    __syncthreads();
    out[b * 130 + t] = xg[b * HID + t];
    if (t == 0) {
        out[b * 130 + 128] = s[0] + s[2] + bo[0];
        out[b * 130 + 129] = s[1] + s[3] + bo[1];
    }
}

extern "C" void kernel_launch(void* const* d_in, const int* in_sizes, int n_in,
                              void* d_out, int out_size, void* d_ws, size_t ws_size,
                              hipStream_t stream)
{
    const float* x    = (const float*)d_in[0];
    const int*   ei   = (const int*)d_in[1];
    const int*   batch= (const int*)d_in[2];
    const float* cell = (const float*)d_in[3];
    const float* W1   = (const float*)d_in[4];
    const float* as1  = (const float*)d_in[5];
    const float* ad1  = (const float*)d_in[6];
    const float* b1   = (const float*)d_in[7];
    const float* W2   = (const float*)d_in[8];
    const float* as2  = (const float*)d_in[9];
    const float* ad2  = (const float*)d_in[10];
    const float* b2   = (const float*)d_in[11];
    const float* Wg   = (const float*)d_in[12];
    const float* bg   = (const float*)d_in[13];
    const float* Wf1  = (const float*)d_in[14];
    const float* bf1  = (const float*)d_in[15];
    const float* Wf2  = (const float*)d_in[16];
    const float* bf2  = (const float*)d_in[17];
    const float* Wf3  = (const float*)d_in[18];
    const float* bf3  = (const float*)d_in[19];
    const float* Wo   = (const float*)d_in[20];
    const float* bo   = (const float*)d_in[21];
    float* out = (float*)d_out;

    char* w = (char*)d_ws;
    auto alloc = [&](size_t bytes) { char* p = w; w += (bytes + 255) & ~(size_t)255; return p; };
    unsigned short* xb   = (unsigned short*)alloc((size_t)N_NODES * KPAD1 * 2);   // 3.1 MB
    unsigned short* W1T  = (unsigned short*)alloc((size_t)F1 * KPAD1 * 2);
    unsigned short* H1   = (unsigned short*)alloc((size_t)N_NODES * F1 * 2);      // 42 MB
    unsigned short* x1   = (unsigned short*)alloc((size_t)N_NODES * F1 * 2);      // 42 MB
    unsigned short* W2T  = (unsigned short*)alloc((size_t)HID * F1 * 2);
    float*    es1  = (float*)alloc((size_t)N_NODES * HEADS * 4);
    float*    ed1  = (float*)alloc((size_t)N_NODES * HEADS * 4);
    float*    H2   = (float*)alloc((size_t)N_NODES * HID * 4);
    float*    x2   = (float*)alloc((size_t)N_NODES * HID * 4);
    float*    es2  = (float*)alloc((size_t)N_NODES * 4);
    float*    ed2  = (float*)alloc((size_t)N_NODES * 4);
    int*      counts    = (int*)alloc((size_t)N_NODES * 4);
    int*      row_start = (int*)alloc((size_t)(N_NODES + 1) * 4);
    int*      cursor    = (int*)alloc((size_t)N_NODES * 4);
    int*      csr_src   = (int*)alloc((size_t)ETOT * 4);
    unsigned* pk   = (unsigned*)alloc((size_t)BGRAPH * HID * 4);
    unsigned short* pooledb = (unsigned short*)alloc((size_t)BGRAPH * HID * 2);
    unsigned short* WgT  = (unsigned short*)alloc((size_t)HID * HID * 2);
    float*    xga  = (float*)alloc((size_t)BGRAPH * HID * 4);
    float*    xg   = (float*)alloc((size_t)BGRAPH * HID * 4);
    unsigned short* celln = (unsigned short*)alloc((size_t)BGRAPH * KPADC * 2);
    unsigned short* Wf1T = (unsigned short*)alloc((size_t)2048 * KPADC * 2);      // 3.9 MB
    unsigned short* Wf2T = (unsigned short*)alloc((size_t)512 * 2048 * 2);
    unsigned short* Wf3T = (unsigned short*)alloc((size_t)HID * 512 * 2);
    float*    xc1a = (float*)alloc((size_t)BGRAPH * 2048 * 4);
    unsigned short* xc1b = (unsigned short*)alloc((size_t)BGRAPH * 2048 * 2);
    float*    xc2a = (float*)alloc((size_t)BGRAPH * 512 * 4);
    unsigned short* xc2b = (unsigned short*)alloc((size_t)BGRAPH * 512 * 2);
    float*    xc3a = (float*)alloc((size_t)BGRAPH * HID * 4);
    float*    xc3  = (float*)alloc((size_t)BGRAPH * HID * 4);

    hipMemsetAsync(counts, 0, (size_t)N_NODES * 4, stream);
    hipMemsetAsync(pk,     0, (size_t)BGRAPH * HID * 4, stream);
    hipMemsetAsync(xga,    0, (size_t)BGRAPH * HID * 4, stream);
    hipMemsetAsync(xc1a,   0, (size_t)BGRAPH * 2048 * 4, stream);
    hipMemsetAsync(xc2a,   0, (size_t)BGRAPH * 512 * 4, stream);
    hipMemsetAsync(xc3a,   0, (size_t)BGRAPH * HID * 4, stream);

    dim3 b256(256);
    const int egrid = (ETOT + 255) / 256;

    // ---- CSR build ----
    hist_dst<<<egrid, b256, 0, stream>>>(ei, counts);
    scan_counts<<<1, b256, 0, stream>>>(counts, row_start, cursor);
    scatter_csr<<<egrid, b256, 0, stream>>>(ei, cursor, csr_src);

    // ---- weight prep ----
    convert_x<<<(N_NODES * KPAD1 + 255) / 256, b256, 0, stream>>>(x, xb);
    transpose_w<<<(F1 * KPAD1 + 255) / 256, b256, 0, stream>>>(W1, W1T, F_INPUT, F1, KPAD1);
    transpose_w<<<(HID * F1 + 255) / 256, b256, 0, stream>>>(W2, W2T, F1, HID, F1);
    transpose_w<<<(2048 * KPADC + 255) / 256, b256, 0, stream>>>(Wf1, Wf1T, F_CELL, 2048, KPADC);
    transpose_w<<<(512 * 2048 + 255) / 256, b256, 0, stream>>>(Wf2, Wf2T, 2048, 512, 2048);
    transpose_w<<<(HID * 512 + 255) / 256, b256, 0, stream>>>(Wf3, Wf3T, 512, HID, 512);
    transpose_w<<<(HID * HID + 255) / 256, b256, 0, stream>>>(Wg, WgT, HID, HID, HID);

    // ---- GAT layer 1: H1 = x @ W1 (bf16 MFMA, 128x128 tiles) ----
    mfma_gemm<4, 4, 1><<<dim3(F1 / 128, N_NODES / 128, 1), b256, 0, stream>>>(
        xb, W1T, H1, N_NODES, F1, KPAD1, KPAD1 / 32);
    attn_coef1<<<N_NODES, 64, 0, stream>>>((const __hip_bfloat16*)H1, as1, ad1, es1, ed1);
    gat1_agg<<<N_NODES, b256, 0, stream>>>(row_start, csr_src, (const __hip_bfloat16*)H1,
                                           es1, ed1, b1, x1);

    // ---- GAT layer 2: H2 = x1 @ W2 (64x128 tiles -> 256 blocks) ----
    mfma_gemm<2, 4, 0><<<dim3(1, N_NODES / 64, 1), b256, 0, stream>>>(
        x1, W2T, H2, N_NODES, HID, F1, F1 / 32);
    attn_coef2<<<N_NODES, 64, 0, stream>>>(H2, as2, ad2, es2, ed2);
    gat2_agg<<<N_NODES, 64, 0, stream>>>(row_start, csr_src, H2, es2, ed2, b2, x2);

    // ---- pool + drug fc (split-K atomic) ----
    pool_max<<<(N_NODES * HID + 255) / 256, b256, 0, stream>>>(x2, batch, pk);
    decode_keys_bf16<<<(BGRAPH * HID + 255) / 256, b256, 0, stream>>>(pk, pooledb, BGRAPH * HID);
    mfma_gemm<2, 2, 2><<<dim3(HID / 64, BGRAPH / 64, 4), b256, 0, stream>>>(
        pooledb, WgT, xga, BGRAPH, HID, HID, 1);
    epi_relu<0><<<(BGRAPH * HID + 255) / 256, b256, 0, stream>>>(xga, bg, xg, BGRAPH, HID);

    // ---- cell branch ----
    cell_norm<<<BGRAPH, b256, 0, stream>>>(cell, celln);
    mfma_gemm<2, 2, 2><<<dim3(2048 / 64, BGRAPH / 64, 5), b256, 0, stream>>>(
        celln, Wf1T, xc1a, BGRAPH, 2048, KPADC, 6);
    epi_relu<1><<<(BGRAPH * 2048 + 255) / 256, b256, 0, stream>>>(xc1a, bf1, xc1b, BGRAPH, 2048);
    mfma_gemm<2, 2, 2><<<dim3(512 / 64, BGRAPH / 64, 16), b256, 0, stream>>>(
        xc1b, Wf2T, xc2a, BGRAPH, 512, 2048, 4);
    epi_relu<1><<<(BGRAPH * 512 + 255) / 256, b256, 0, stream>>>(xc2a, bf2, xc2b, BGRAPH, 512);
    mfma_gemm<2, 2, 2><<<dim3(HID / 64, BGRAPH / 64, 8), b256, 0, stream>>>(
        xc2b, Wf3T, xc3a, BGRAPH, HID, 512, 2);
    epi_relu<0><<<(BGRAPH * HID + 255) / 256, b256, 0, stream>>>(xc3a, bf3, xc3, BGRAPH, HID);

    // ---- output head + concat ----
    final_out<<<BGRAPH, 128, 0, stream>>>(xg, xc3, Wo, bo, out);
}

// Round 4
// 295.470 us; speedup vs baseline: 5.3255x; 1.1691x over previous
//
#include <hip/hip_runtime.h>
#include <hip/hip_bf16.h>
#include <math.h>

#define N_NODES 16384
#define E_EDGES 131072
#define ETOT (E_EDGES + N_NODES)   // 147456 (self-loops appended)
#define BGRAPH 256
#define F_INPUT 78
#define KPAD1 96                   // F_INPUT padded to mult of 32
#define HID 128
#define HEADS 10
#define F1 (HEADS * HID)           // 1280
#define F_CELL 954
#define KPADC 960                  // F_CELL padded
#define NEG_SLOPE 0.2f

typedef __attribute__((ext_vector_type(8))) short frag_t;   // 8 bf16
typedef __attribute__((ext_vector_type(4))) float f4_t;
typedef __attribute__((ext_vector_type(8))) unsigned short u16x8;

static __device__ __forceinline__ unsigned fkey(float f) {
    unsigned b = __float_as_uint(f);
    return (b & 0x80000000u) ? ~b : (b | 0x80000000u);
}
static __device__ __forceinline__ float funkey(unsigned k) {
    unsigned b = (k & 0x80000000u) ? (k ^ 0x80000000u) : ~k;
    return __uint_as_float(b);
}
static __device__ __forceinline__ unsigned short f2bf(float f) {
    __hip_bfloat16 h = __float2bfloat16(f);
    return *(unsigned short*)&h;
}
static __device__ __forceinline__ float bf2f(unsigned short u) {
    return __uint_as_float(((unsigned)u) << 16);
}

// ================= MFMA bf16 GEMM =================
// A [M,Kpad] bf16, BT [N,Kpad] bf16 (B transposed). C row-major [M,N].
// OUT: 0 = f32 store, 1 = bf16 store, 2 = f32 atomicAdd (split-K).
template<int WM16, int WN16, int OUT>
__global__ __launch_bounds__(256) void mfma_gemm(
    const unsigned short* __restrict__ A, const unsigned short* __restrict__ BT,
    void* __restrict__ C, int M, int N, int Kpad, int ksteps)
{
    constexpr int BM = 32 * WM16, BN = 32 * WN16;
    __shared__ __align__(16) unsigned short Als[BM * 32];
    __shared__ __align__(16) unsigned short Bls[BN * 32];
    const int t = threadIdx.x;
    const int wave = t >> 6, lane = t & 63;
    const int wr = (wave >> 1) * (16 * WM16);
    const int wc = (wave & 1) * (16 * WN16);
    const int row0 = blockIdx.y * BM;
    const int col0 = blockIdx.x * BN;
    int kk = blockIdx.z * ksteps * 32;
    const int kend = min(kk + ksteps * 32, Kpad);

    f4_t acc[WM16][WN16];
#pragma unroll
    for (int m = 0; m < WM16; m++)
#pragma unroll
        for (int n = 0; n < WN16; n++) { acc[m][n] = (f4_t){0.f, 0.f, 0.f, 0.f}; }

    const int lrow = lane & 15, kg = lane >> 4;
    for (; kk < kend; kk += 32) {
#pragma unroll
        for (int p = 0; p < BM / 64; p++) {
            int i = t + p * 256;
            int r = i >> 2, slot = i & 3;
            uint4 v = *(const uint4*)&A[(size_t)(row0 + r) * Kpad + kk + slot * 8];
            *(uint4*)&Als[r * 32 + ((slot ^ (r & 3) ^ ((r >> 2) & 3)) * 8)] = v;
        }
#pragma unroll
        for (int p = 0; p < BN / 64; p++) {
            int i = t + p * 256;
            int r = i >> 2, slot = i & 3;
            uint4 v = *(const uint4*)&BT[(size_t)(col0 + r) * Kpad + kk + slot * 8];
            *(uint4*)&Bls[r * 32 + ((slot ^ (r & 3) ^ ((r >> 2) & 3)) * 8)] = v;
        }
        __syncthreads();
        frag_t af[WM16], bfr[WN16];
#pragma unroll
        for (int m = 0; m < WM16; m++) {
            int r = wr + m * 16 + lrow;
            af[m] = *(frag_t*)&Als[r * 32 + ((kg ^ (r & 3) ^ ((r >> 2) & 3)) * 8)];
        }
#pragma unroll
        for (int n = 0; n < WN16; n++) {
            int r = wc + n * 16 + lrow;
            bfr[n] = *(frag_t*)&Bls[r * 32 + ((kg ^ (r & 3) ^ ((r >> 2) & 3)) * 8)];
        }
#pragma unroll
        for (int m = 0; m < WM16; m++)
#pragma unroll
            for (int n = 0; n < WN16; n++)
                acc[m][n] = __builtin_amdgcn_mfma_f32_16x16x32_bf16(af[m], bfr[n], acc[m][n], 0, 0, 0);
        __syncthreads();
    }

#pragma unroll
    for (int m = 0; m < WM16; m++) {
#pragma unroll
        for (int n = 0; n < WN16; n++) {
            int col = col0 + wc + n * 16 + lrow;
#pragma unroll
            for (int r = 0; r < 4; r++) {
                int row = row0 + wr + m * 16 + kg * 4 + r;
                float v = acc[m][n][r];
                if (OUT == 0)      ((float*)C)[(size_t)row * N + col] = v;
                else if (OUT == 1) ((unsigned short*)C)[(size_t)row * N + col] = f2bf(v);
                else               atomicAdd(&((float*)C)[(size_t)row * N + col], v);
            }
        }
    }
}

// ================= format conversions =================
__global__ void convert_x(const float* __restrict__ x, unsigned short* __restrict__ xb)
{
    int i = blockIdx.x * blockDim.x + threadIdx.x;
    if (i >= N_NODES * KPAD1) return;
    int r = i / KPAD1, k = i % KPAD1;
    xb[i] = (k < F_INPUT) ? f2bf(x[r * F_INPUT + k]) : 0;
}

__global__ void transpose_w(const float* __restrict__ W, unsigned short* __restrict__ WT,
                            int K, int N, int Kpad)
{
    int i = blockIdx.x * blockDim.x + threadIdx.x;
    if (i >= N * Kpad) return;
    int n = i / Kpad, k = i % Kpad;
    WT[i] = (k < K) ? f2bf(W[(size_t)k * N + n]) : 0;
}

// ================= CSR build (by dst) =================
__global__ void hist_dst(const int* __restrict__ ei, int* __restrict__ counts)
{
    int e = blockIdx.x * blockDim.x + threadIdx.x;
    if (e >= ETOT) return;
    int dst = (e < E_EDGES) ? ei[E_EDGES + e] : (e - E_EDGES);
    atomicAdd(&counts[dst], 1);
}

__global__ void scan_counts(const int* __restrict__ counts,
                            int* __restrict__ row_start, int* __restrict__ cursor)
{
    __shared__ int part[256];
    int t = threadIdx.x;
    int base = t * 64;
    int sum = 0;
    for (int i = 0; i < 64; i++) sum += counts[base + i];
    part[t] = sum;
    __syncthreads();
    for (int o = 1; o < 256; o <<= 1) {
        int v = 0;
        if (t >= o) v = part[t - o];
        __syncthreads();
        part[t] += v;
        __syncthreads();
    }
    int run = (t == 0) ? 0 : part[t - 1];
    for (int i = 0; i < 64; i++) {
        row_start[base + i] = run;
        cursor[base + i] = run;
        run += counts[base + i];
    }
    if (t == 255) row_start[N_NODES] = run;
}

__global__ void scatter_csr(const int* __restrict__ ei, int* __restrict__ cursor,
                            int* __restrict__ csr_src)
{
    int e = blockIdx.x * blockDim.x + threadIdx.x;
    if (e >= ETOT) return;
    int src, dst;
    if (e < E_EDGES) { src = ei[e]; dst = ei[E_EDGES + e]; } else { src = dst = e - E_EDGES; }
    int pos = atomicAdd(&cursor[dst], 1);
    csr_src[pos] = src;
}

// ================= attention coefficients =================
// layer 1: H bf16 [N,1280]; lane covers channels (2l, 2l+1) of each head via u32 loads
__global__ void attn_coef1(const unsigned short* __restrict__ H,
                           const float* __restrict__ as_, const float* __restrict__ ad_,
                           float* __restrict__ es, float* __restrict__ ed)
{
    int n = blockIdx.x, l = threadIdx.x;  // 64 threads
    const unsigned* row32 = (const unsigned*)(H + (size_t)n * F1);
#pragma unroll
    for (int h = 0; h < HEADS; h++) {
        unsigned p = row32[h * 64 + l];
        float h0 = __uint_as_float(p << 16);
        float h1 = __uint_as_float(p & 0xffff0000u);
        float2 av = *(const float2*)&as_[h * HID + 2 * l];
        float2 dv = *(const float2*)&ad_[h * HID + 2 * l];
        float vs = h0 * av.x + h1 * av.y;
        float vd = h0 * dv.x + h1 * dv.y;
#pragma unroll
        for (int o = 32; o > 0; o >>= 1) { vs += __shfl_down(vs, o); vd += __shfl_down(vd, o); }
        if (l == 0) { es[n * HEADS + h] = vs; ed[n * HEADS + h] = vd; }
    }
}

__global__ void attn_coef2(const float* __restrict__ H,
                           const float* __restrict__ as_, const float* __restrict__ ad_,
                           float* __restrict__ es, float* __restrict__ ed)
{
    int n = blockIdx.x, l = threadIdx.x;  // 64 threads
    const float* row = H + (size_t)n * HID;
    float2 hv = *(const float2*)&row[2 * l];
    float2 av = *(const float2*)&as_[2 * l];
    float2 dv = *(const float2*)&ad_[2 * l];
    float vs = hv.x * av.x + hv.y * av.y;
    float vd = hv.x * dv.x + hv.y * dv.y;
#pragma unroll
    for (int o = 32; o > 0; o >>= 1) { vs += __shfl_down(vs, o); vd += __shfl_down(vd, o); }
    if (l == 0) { es[n] = vs; ed[n] = vd; }
}

// ================= GAT layer-1 aggregation: WAVE per dst node =================
// 4 nodes per 256-thread block. Lanes = edges for softmax (shfl reductions);
// channel-parallel ushort8 gather for the weighted sum. No __syncthreads.
__global__ __launch_bounds__(256) void gat1_agg(
    const int* __restrict__ row_start, const int* __restrict__ csr_src,
    const unsigned short* __restrict__ H,
    const float* __restrict__ es, const float* __restrict__ ed,
    const float* __restrict__ b, unsigned short* __restrict__ xout)
{
    const int w = threadIdx.x >> 6, l = threadIdx.x & 63;
    const int n = blockIdx.x * 4 + w;
    const int rs = row_start[n];
    const int deg = row_start[n + 1] - rs;
    const int hi = l >> 4;   // 16-lane group -> head sub-index

    __shared__ float w_lds[4][64][11];   // stride 11: conflict-free
    __shared__ int   src_lds[4][64];

    float edv[HEADS];
    const float* edp = ed + n * HEADS;
#pragma unroll
    for (int h = 0; h < HEADS; h++) edv[h] = edp[h];

    // ---- pass A: per-head max (lanes = edges) ----
    float m[HEADS];
#pragma unroll
    for (int h = 0; h < HEADS; h++) m[h] = -INFINITY;
    for (int base = 0; base < deg; base += 64) {
        int e = base + l;
        if (e < deg) {
            int s = csr_src[rs + e];
            const float* ep = es + s * HEADS;
#pragma unroll
            for (int h = 0; h < HEADS; h++) {
                float v = ep[h] + edv[h];
                v = (v >= 0.f) ? v : NEG_SLOPE * v;
                m[h] = fmaxf(m[h], v);
            }
        }
    }
#pragma unroll
    for (int h = 0; h < HEADS; h++)
#pragma unroll
        for (int o = 32; o > 0; o >>= 1) m[h] = fmaxf(m[h], __shfl_xor(m[h], o));

    // ---- pass B: weights + channel-parallel accumulation ----
    float acc[3][8];
#pragma unroll
    for (int s0 = 0; s0 < 3; s0++)
#pragma unroll
        for (int k = 0; k < 8; k++) acc[s0][k] = 0.f;
    float den[HEADS];
#pragma unroll
    for (int h = 0; h < HEADS; h++) den[h] = 0.f;

    for (int base = 0; base < deg; base += 64) {
        int e = base + l;
        int cnt = min(64, deg - base);
        float wv[HEADS];
        if (e < deg) {
            int s = csr_src[rs + e];
            src_lds[w][l] = s;
            const float* ep = es + s * HEADS;
#pragma unroll
            for (int h = 0; h < HEADS; h++) {
                float v = ep[h] + edv[h];
                v = (v >= 0.f) ? v : NEG_SLOPE * v;
                wv[h] = __expf(v - m[h]);
            }
        } else {
#pragma unroll
            for (int h = 0; h < HEADS; h++) wv[h] = 0.f;
        }
#pragma unroll
        for (int h = 0; h < HEADS; h++) {
            den[h] += wv[h];
            w_lds[w][l][h] = wv[h];
        }
        // wave-synchronous LDS: DS ops from one wave complete in order; just
        // stop the compiler from reordering the reads above the writes.
        asm volatile("" ::: "memory");

        for (int j = 0; j < cnt; j++) {
            int sj = src_lds[w][j];
            const unsigned short* hrow = H + (size_t)sj * F1;
#pragma unroll
            for (int slot = 0; slot < 3; slot++) {
                if (slot < 2 || l < 32) {
                    int c0 = slot * 512 + l * 8;
                    float wj = w_lds[w][j][slot * 4 + hi];
                    u16x8 v = *(const u16x8*)&hrow[c0];
#pragma unroll
                    for (int k = 0; k < 8; k++)
                        acc[slot][k] = fmaf(wj, bf2f((unsigned short)v[k]), acc[slot][k]);
                }
            }
        }
        asm volatile("" ::: "memory");
    }

#pragma unroll
    for (int h = 0; h < HEADS; h++)
#pragma unroll
        for (int o = 32; o > 0; o >>= 1) den[h] += __shfl_xor(den[h], o);

    // ---- epilogue: /den + bias + elu, bf16 store ----
    unsigned short* orow = xout + (size_t)n * F1;
#pragma unroll
    for (int slot = 0; slot < 3; slot++) {
        if (slot < 2 || l < 32) {
            int c0 = slot * 512 + l * 8;
            float dh;
            if (slot == 2) dh = (hi == 0) ? den[8] : den[9];
            else dh = (hi == 0) ? den[slot * 4] : (hi == 1) ? den[slot * 4 + 1]
                    : (hi == 2) ? den[slot * 4 + 2] : den[slot * 4 + 3];
            float inv = 1.f / dh;
            float4 b0 = *(const float4*)&b[c0];
            float4 b1 = *(const float4*)&b[c0 + 4];
            float bb[8] = {b0.x, b0.y, b0.z, b0.w, b1.x, b1.y, b1.z, b1.w};
            u16x8 ov;
#pragma unroll
            for (int k = 0; k < 8; k++) {
                float v = acc[slot][k] * inv + bb[k];
                ov[k] = f2bf((v > 0.f) ? v : expm1f(v));
            }
            *(u16x8*)&orow[c0] = ov;
        }
    }
}

// ================= GAT layer-2 aggregation: WAVE per dst node =================
// Pure-register: w/src broadcast via shfl; float2 channel gather.
__global__ __launch_bounds__(256) void gat2_agg(
    const int* __restrict__ row_start, const int* __restrict__ csr_src,
    const float* __restrict__ H,
    const float* __restrict__ es, const float* __restrict__ ed,
    const float* __restrict__ b, float* __restrict__ xout)
{
    const int w = threadIdx.x >> 6, l = threadIdx.x & 63;
    const int n = blockIdx.x * 4 + w;
    const int rs = row_start[n];
    const int deg = row_start[n + 1] - rs;
    const float edv = ed[n];

    float m = -INFINITY;
    for (int base = 0; base < deg; base += 64) {
        int e = base + l;
        if (e < deg) {
            int s = csr_src[rs + e];
            float v = es[s] + edv;
            v = (v >= 0.f) ? v : NEG_SLOPE * v;
            m = fmaxf(m, v);
        }
    }
#pragma unroll
    for (int o = 32; o > 0; o >>= 1) m = fmaxf(m, __shfl_xor(m, o));

    float2 acc = {0.f, 0.f};
    float den = 0.f;
    for (int base = 0; base < deg; base += 64) {
        int e = base + l;
        int cnt = min(64, deg - base);
        int s = 0;
        float wv = 0.f;
        if (e < deg) {
            s = csr_src[rs + e];
            float v = es[s] + edv;
            v = (v >= 0.f) ? v : NEG_SLOPE * v;
            wv = __expf(v - m);
        }
        den += wv;
        for (int j = 0; j < cnt; j++) {
            float wj = __shfl(wv, j);
            int   sj = __shfl(s, j);
            float2 hv = *(const float2*)(H + (size_t)sj * HID + 2 * l);
            acc.x = fmaf(wj, hv.x, acc.x);
            acc.y = fmaf(wj, hv.y, acc.y);
        }
    }
#pragma unroll
    for (int o = 32; o > 0; o >>= 1) den += __shfl_xor(den, o);

    float inv = 1.f / den;
    float2 bv = *(const float2*)&b[2 * l];
    float v0 = acc.x * inv + bv.x;
    float v1 = acc.y * inv + bv.y;
    float2 ov;
    ov.x = (v0 > 0.f) ? v0 : expm1f(v0);
    ov.y = (v1 > 0.f) ? v1 : expm1f(v1);
    *(float2*)(xout + (size_t)n * HID + 2 * l) = ov;
}

// ================= pool / cell / epilogues =================
__global__ void pool_max(const float* __restrict__ x2, const int* __restrict__ batch,
                         unsigned* __restrict__ pk)
{
    int idx = blockIdx.x * blockDim.x + threadIdx.x;
    if (idx >= N_NODES * HID) return;
    int n = idx >> 7, c = idx & 127;
    atomicMax(&pk[batch[n] * HID + c], fkey(x2[idx]));
}

__global__ void decode_keys_bf16(const unsigned* __restrict__ pk, unsigned short* __restrict__ outb,
                                 int count)
{
    int i = blockIdx.x * blockDim.x + threadIdx.x;
    if (i < count) outb[i] = f2bf(funkey(pk[i]));
}

__global__ void cell_norm(const float* __restrict__ cell, unsigned short* __restrict__ celln)
{
    int b = blockIdx.x;     // 256 rows
    int t = threadIdx.x;    // 256 threads
    __shared__ float red[256];
    float s = 0.f;
    for (int c = t; c < F_CELL; c += 256) { float v = cell[(size_t)b * F_CELL + c]; s += v * v; }
    red[t] = s; __syncthreads();
    for (int o = 128; o > 0; o >>= 1) { if (t < o) red[t] += red[t + o]; __syncthreads(); }
    float inv = 1.f / fmaxf(sqrtf(red[0]), 1e-12f);
    for (int c = t; c < KPADC; c += 256) {
        float v = (c < F_CELL) ? cell[(size_t)b * F_CELL + c] * inv : 0.f;
        celln[(size_t)b * KPADC + c] = f2bf(v);
    }
}

template<int OUT_BF16>
__global__ void epi_relu(const float* __restrict__ acc, const float* __restrict__ bias,
                         void* __restrict__ out, int rows, int cols)
{
    int i = blockIdx.x * blockDim.x + threadIdx.x;
    if (i >= rows * cols) return;
    int c = i % cols;
    float v = fmaxf(acc[i] + bias[c], 0.f);
    if (OUT_BF16) ((unsigned short*)out)[i] = f2bf(v);
    else          ((float*)out)[i] = v;
}

__global__ void final_out(const float* __restrict__ xg, const float* __restrict__ xc3,
                          const float* __restrict__ Wo, const float* __restrict__ bo,
                          float* __restrict__ out)
{
    int b = blockIdx.x, t = threadIdx.x;   // 128 threads
    float v = xc3[b * HID + t];
    float p0 = v * Wo[t * 2], p1 = v * Wo[t * 2 + 1];
    __shared__ float s[4];
#pragma unroll
    for (int o = 32; o > 0; o >>= 1) { p0 += __shfl_down(p0, o); p1 += __shfl_down(p1, o); }
    if ((t & 63) == 0) { s[(t >> 6) * 2] = p0; s[(t >> 6) * 2 + 1] = p1; }
    __syncthreads();
    out[b * 130 + t] = xg[b * HID + t];
    if (t == 0) {
        out[b * 130 + 128] = s[0] + s[2] + bo[0];
        out[b * 130 + 129] = s[1] + s[3] + bo[1];
    }
}

extern "C" void kernel_launch(void* const* d_in, const int* in_sizes, int n_in,
                              void* d_out, int out_size, void* d_ws, size_t ws_size,
                              hipStream_t stream)
{
    const float* x    = (const float*)d_in[0];
    const int*   ei   = (const int*)d_in[1];
    const int*   batch= (const int*)d_in[2];
    const float* cell = (const float*)d_in[3];
    const float* W1   = (const float*)d_in[4];
    const float* as1  = (const float*)d_in[5];
    const float* ad1  = (const float*)d_in[6];
    const float* b1   = (const float*)d_in[7];
    const float* W2   = (const float*)d_in[8];
    const float* as2  = (const float*)d_in[9];
    const float* ad2  = (const float*)d_in[10];
    const float* b2   = (const float*)d_in[11];
    const float* Wg   = (const float*)d_in[12];
    const float* bg   = (const float*)d_in[13];
    const float* Wf1  = (const float*)d_in[14];
    const float* bf1  = (const float*)d_in[15];
    const float* Wf2  = (const float*)d_in[16];
    const float* bf2  = (const float*)d_in[17];
    const float* Wf3  = (const float*)d_in[18];
    const float* bf3  = (const float*)d_in[19];
    const float* Wo   = (const float*)d_in[20];
    const float* bo   = (const float*)d_in[21];
    float* out = (float*)d_out;

    char* w = (char*)d_ws;
    auto alloc = [&](size_t bytes) { char* p = w; w += (bytes + 255) & ~(size_t)255; return p; };
    unsigned short* xb   = (unsigned short*)alloc((size_t)N_NODES * KPAD1 * 2);
    unsigned short* W1T  = (unsigned short*)alloc((size_t)F1 * KPAD1 * 2);
    unsigned short* H1   = (unsigned short*)alloc((size_t)N_NODES * F1 * 2);      // 42 MB
    unsigned short* x1   = (unsigned short*)alloc((size_t)N_NODES * F1 * 2);      // 42 MB
    unsigned short* W2T  = (unsigned short*)alloc((size_t)HID * F1 * 2);
    float*    es1  = (float*)alloc((size_t)N_NODES * HEADS * 4);
    float*    ed1  = (float*)alloc((size_t)N_NODES * HEADS * 4);
    float*    H2   = (float*)alloc((size_t)N_NODES * HID * 4);
    float*    x2   = (float*)alloc((size_t)N_NODES * HID * 4);
    float*    es2  = (float*)alloc((size_t)N_NODES * 4);
    float*    ed2  = (float*)alloc((size_t)N_NODES * 4);
    int*      counts    = (int*)alloc((size_t)N_NODES * 4);
    int*      row_start = (int*)alloc((size_t)(N_NODES + 1) * 4);
    int*      cursor    = (int*)alloc((size_t)N_NODES * 4);
    int*      csr_src   = (int*)alloc((size_t)ETOT * 4);
    unsigned* pk   = (unsigned*)alloc((size_t)BGRAPH * HID * 4);
    unsigned short* pooledb = (unsigned short*)alloc((size_t)BGRAPH * HID * 2);
    unsigned short* WgT  = (unsigned short*)alloc((size_t)HID * HID * 2);
    float*    xga  = (float*)alloc((size_t)BGRAPH * HID * 4);
    float*    xg   = (float*)alloc((size_t)BGRAPH * HID * 4);
    unsigned short* celln = (unsigned short*)alloc((size_t)BGRAPH * KPADC * 2);
    unsigned short* Wf1T = (unsigned short*)alloc((size_t)2048 * KPADC * 2);
    unsigned short* Wf2T = (unsigned short*)alloc((size_t)512 * 2048 * 2);
    unsigned short* Wf3T = (unsigned short*)alloc((size_t)HID * 512 * 2);
    float*    xc1a = (float*)alloc((size_t)BGRAPH * 2048 * 4);
    unsigned short* xc1b = (unsigned short*)alloc((size_t)BGRAPH * 2048 * 2);
    float*    xc2a = (float*)alloc((size_t)BGRAPH * 512 * 4);
    unsigned short* xc2b = (unsigned short*)alloc((size_t)BGRAPH * 512 * 2);
    float*    xc3a = (float*)alloc((size_t)BGRAPH * HID * 4);
    float*    xc3  = (float*)alloc((size_t)BGRAPH * HID * 4);

    hipMemsetAsync(counts, 0, (size_t)N_NODES * 4, stream);
    hipMemsetAsync(pk,     0, (size_t)BGRAPH * HID * 4, stream);
    hipMemsetAsync(xga,    0, (size_t)BGRAPH * HID * 4, stream);
    hipMemsetAsync(xc1a,   0, (size_t)BGRAPH * 2048 * 4, stream);
    hipMemsetAsync(xc2a,   0, (size_t)BGRAPH * 512 * 4, stream);
    hipMemsetAsync(xc3a,   0, (size_t)BGRAPH * HID * 4, stream);

    dim3 b256(256);
    const int egrid = (ETOT + 255) / 256;

    // ---- CSR build ----
    hist_dst<<<egrid, b256, 0, stream>>>(ei, counts);
    scan_counts<<<1, b256, 0, stream>>>(counts, row_start, cursor);
    scatter_csr<<<egrid, b256, 0, stream>>>(ei, cursor, csr_src);

    // ---- weight prep ----
    convert_x<<<(N_NODES * KPAD1 + 255) / 256, b256, 0, stream>>>(x, xb);
    transpose_w<<<(F1 * KPAD1 + 255) / 256, b256, 0, stream>>>(W1, W1T, F_INPUT, F1, KPAD1);
    transpose_w<<<(HID * F1 + 255) / 256, b256, 0, stream>>>(W2, W2T, F1, HID, F1);
    transpose_w<<<(2048 * KPADC + 255) / 256, b256, 0, stream>>>(Wf1, Wf1T, F_CELL, 2048, KPADC);
    transpose_w<<<(512 * 2048 + 255) / 256, b256, 0, stream>>>(Wf2, Wf2T, 2048, 512, 2048);
    transpose_w<<<(HID * 512 + 255) / 256, b256, 0, stream>>>(Wf3, Wf3T, 512, HID, 512);
    transpose_w<<<(HID * HID + 255) / 256, b256, 0, stream>>>(Wg, WgT, HID, HID, HID);

    // ---- GAT layer 1 ----
    mfma_gemm<4, 4, 1><<<dim3(F1 / 128, N_NODES / 128, 1), b256, 0, stream>>>(
        xb, W1T, H1, N_NODES, F1, KPAD1, KPAD1 / 32);
    attn_coef1<<<N_NODES, 64, 0, stream>>>(H1, as1, ad1, es1, ed1);
    gat1_agg<<<N_NODES / 4, b256, 0, stream>>>(row_start, csr_src, H1, es1, ed1, b1, x1);

    // ---- GAT layer 2 ----
    mfma_gemm<2, 4, 0><<<dim3(1, N_NODES / 64, 1), b256, 0, stream>>>(
        x1, W2T, H2, N_NODES, HID, F1, F1 / 32);
    attn_coef2<<<N_NODES, 64, 0, stream>>>(H2, as2, ad2, es2, ed2);
    gat2_agg<<<N_NODES / 4, b256, 0, stream>>>(row_start, csr_src, H2, es2, ed2, b2, x2);

    // ---- pool + drug fc ----
    pool_max<<<(N_NODES * HID + 255) / 256, b256, 0, stream>>>(x2, batch, pk);
    decode_keys_bf16<<<(BGRAPH * HID + 255) / 256, b256, 0, stream>>>(pk, pooledb, BGRAPH * HID);
    mfma_gemm<2, 2, 2><<<dim3(HID / 64, BGRAPH / 64, 4), b256, 0, stream>>>(
        pooledb, WgT, xga, BGRAPH, HID, HID, 1);
    epi_relu<0><<<(BGRAPH * HID + 255) / 256, b256, 0, stream>>>(xga, bg, xg, BGRAPH, HID);

    // ---- cell branch ----
    cell_norm<<<BGRAPH, b256, 0, stream>>>(cell, celln);
    mfma_gemm<2, 2, 2><<<dim3(2048 / 64, BGRAPH / 64, 5), b256, 0, stream>>>(
        celln, Wf1T, xc1a, BGRAPH, 2048, KPADC, 6);
    epi_relu<1><<<(BGRAPH * 2048 + 255) / 256, b256, 0, stream>>>(xc1a, bf1, xc1b, BGRAPH, 2048);
    mfma_gemm<2, 2, 2><<<dim3(512 / 64, BGRAPH / 64, 16), b256, 0, stream>>>(
        xc1b, Wf2T, xc2a, BGRAPH, 512, 2048, 4);
    epi_relu<1><<<(BGRAPH * 512 + 255) / 256, b256, 0, stream>>>(xc2a, bf2, xc2b, BGRAPH, 512);
    mfma_gemm<2, 2, 2><<<dim3(HID / 64, BGRAPH / 64, 8), b256, 0, stream>>>(
        xc2b, Wf3T, xc3a, BGRAPH, HID, 512, 2);
    epi_relu<0><<<(BGRAPH * HID + 255) / 256, b256, 0, stream>>>(xc3a, bf3, xc3, BGRAPH, HID);

    // ---- output head + concat ----
    final_out<<<BGRAPH, 128, 0, stream>>>(xg, xc3, Wo, bo, out);
}